// Round 4
// baseline (1277.877 us; speedup 1.0000x reference)
//
#include <hip/hip_runtime.h>
#include <hip/hip_bf16.h>
#include <cstdint>

#define DEV static __device__ __forceinline__

typedef __attribute__((ext_vector_type(8))) __bf16 bf16x8;
typedef __attribute__((ext_vector_type(4))) float f32x4;
typedef __attribute__((ext_vector_type(8))) unsigned short ushort8;

constexpr int NTOK = 65536;
constexpr int E = 1024;

DEV unsigned short f2b(float f) {
  unsigned int u = __builtin_bit_cast(unsigned int, f);
  u += 0x7fffu + ((u >> 16) & 1u);
  return (unsigned short)(u >> 16);
}

DEV f32x4 mfma16(bf16x8 a, bf16x8 b, f32x4 c) {
  return __builtin_amdgcn_mfma_f32_16x16x32_bf16(a, b, c, 0, 0, 0);
}

DEV void gload16(const void* g, const void* l) {
  __builtin_amdgcn_global_load_lds(
      (const __attribute__((address_space(1))) void*)g,
      (__attribute__((address_space(3))) void*)l, 16, 0, 0);
}

DEV void BAR() {
  asm volatile("" ::: "memory");
  __builtin_amdgcn_s_barrier();
  asm volatile("" ::: "memory");
  __builtin_amdgcn_sched_barrier(0);
}

#define WAITVM(n_) do { \
  asm volatile("s_waitcnt vmcnt(" #n_ ")" ::: "memory"); \
  __builtin_amdgcn_sched_barrier(0); \
} while (0)

#define WAITLGKM0() do { \
  asm volatile("s_waitcnt lgkmcnt(0)" ::: "memory"); \
  __builtin_amdgcn_sched_barrier(0); \
} while (0)

// ---------------- fp32 -> bf16 converts ----------------
__global__ void cvt8(const float* __restrict__ in, unsigned short* __restrict__ out,
                     int n8) {
  int i = blockIdx.x * blockDim.x + threadIdx.x;
  if (i >= n8) return;
  const float4* p = (const float4*)(in + (size_t)i * 8);
  float4 a = p[0], b = p[1];
  ushort8 r;
  r[0] = f2b(a.x); r[1] = f2b(a.y); r[2] = f2b(a.z); r[3] = f2b(a.w);
  r[4] = f2b(b.x); r[5] = f2b(b.y); r[6] = f2b(b.z); r[7] = f2b(b.w);
  *(ushort8*)(out + (size_t)i * 8) = r;
}

// All four weights in one launch; outputs are contiguous: [Wq|Wk|Wv|Wo] bf16.
__global__ void cvtW(const float* __restrict__ Wq, const float* __restrict__ Wk,
                     const float* __restrict__ Wv, const float* __restrict__ Wo,
                     unsigned short* __restrict__ out) {
  int i = blockIdx.x * blockDim.x + threadIdx.x;  // 0..524287 (4M elems / 8)
  int wsel = i >> 17;
  const float* src = wsel == 0 ? Wq : wsel == 1 ? Wk : wsel == 2 ? Wv : Wo;
  int j = i & 131071;
  const float4* p = (const float4*)(src + (size_t)j * 8);
  float4 a = p[0], b = p[1];
  ushort8 r;
  r[0] = f2b(a.x); r[1] = f2b(a.y); r[2] = f2b(a.z); r[3] = f2b(a.w);
  r[4] = f2b(b.x); r[5] = f2b(b.y); r[6] = f2b(b.z); r[7] = f2b(b.w);
  *(ushort8*)(out + (size_t)i * 8) = r;
}

// ---------------------------------------------------------------------------
// Persistent 256x256-tile GEMM, K=1024 fixed (NT=16), grid = 256 blocks.
// Each block processes `rounds` output tiles as one continuous virtual-K
// stream: the boundary iteration's T+2/T+3 stages are the next tile's k0/k1
// (identical staging cadence -> vmcnt(6) invariant carries across tiles),
// epilogue stores overlap the next tile's already-staged first phases.
// T1 XCD swizzle, T2 st-swizzle, T3/T4 counted vmcnt(6), T5 setprio.
// LDS 128 KiB: A[2buf][2half][128][64]bf16 @0, B same @65536.
// ---------------------------------------------------------------------------
template <typename OutT>
__global__ __launch_bounds__(512, 2) void gemmp(
    const unsigned short* __restrict__ A, const unsigned short* __restrict__ B,
    OutT* __restrict__ C, int N, int nbx, int rounds) {
  __shared__ char smem[131072];
  char* sA = smem;
  char* sB = smem + 65536;

  const int tiles = rounds << 8;
  const int cpx = tiles >> 3;

  const int t = threadIdx.x;
  const int w = t >> 6, l = t & 63;
  const int wr = w >> 2, wc = w & 3;  // 2 x 4 wave grid
  const int lr = l & 15, q = l >> 4;

  // staging lane constants (source column pre-swizzled: slot ^ (row&7))
  const int srow = w * 8 + (l >> 3);
  const int scol = ((l & 7) ^ (l >> 3)) * 8;
  const size_t voff = (size_t)srow * 1024 + scol;  // per-lane element offset
  // ds_read lane constants (same XOR on the read side)
  const int xorv = (lr & 7) << 4;
  const int offk0 = (q * 16) ^ xorv;
  const int offk1 = (64 + q * 16) ^ xorv;
  const int aRB = wr * 8192 + lr * 128;
  const int bRB = wc * 4096 + lr * 128;

  int tm, tn;
  {
    int v = (int)blockIdx.x;
    int wg = (v & 7) * cpx + (v >> 3);
    tm = (wg / nbx) << 8;
    tn = (wg % nbx) << 8;
  }

  // base_ is the tile's tm (for A) or tn (for B); kk_ = K-tile index 0..15
#define STAGE_A(base_, kk_, h_) do { \
    const unsigned short* g_ = A + (((size_t)((base_) + (h_)*128)) << 10) + ((kk_) << 6) + voff; \
    const char* d_ = sA + ((((kk_) & 1) << 15) + (h_)*16384 + w * 1024); \
    gload16(g_, d_); \
    gload16(g_ + (size_t)(64 << 10), d_ + 8192); \
  } while (0)

#define STAGE_B(base_, kk_, h_) do { \
    const unsigned short* g_ = B + (((size_t)((base_) + (h_)*128)) << 10) + ((kk_) << 6) + voff; \
    const char* d_ = sB + ((((kk_) & 1) << 15) + (h_)*16384 + w * 1024); \
    gload16(g_, d_); \
    gload16(g_ + (size_t)(64 << 10), d_ + 8192); \
  } while (0)

  f32x4 acc[8][4] = {};
  bf16x8 af[4][2];
  bf16x8 bf_[2][2][2];

#define LDA(buf_, mh_) do { \
    _Pragma("unroll") for (int m_ = 0; m_ < 4; ++m_) { \
      af[m_][0] = *(const bf16x8*)(sA + (buf_)*32768 + (mh_)*16384 + m_*2048 + aRB + offk0); \
      af[m_][1] = *(const bf16x8*)(sA + (buf_)*32768 + (mh_)*16384 + m_*2048 + aRB + offk1); \
    } \
  } while (0)

#define LDB(buf_, nh_) do { \
    _Pragma("unroll") for (int n_ = 0; n_ < 2; ++n_) { \
      bf_[nh_][n_][0] = *(const bf16x8*)(sB + (buf_)*32768 + (nh_)*16384 + n_*2048 + bRB + offk0); \
      bf_[nh_][n_][1] = *(const bf16x8*)(sB + (buf_)*32768 + (nh_)*16384 + n_*2048 + bRB + offk1); \
    } \
  } while (0)

#define MM(mh_, nh_) do { \
    __builtin_amdgcn_s_setprio(1); \
    _Pragma("unroll") for (int m_ = 0; m_ < 4; ++m_) \
      _Pragma("unroll") for (int n_ = 0; n_ < 2; ++n_) { \
        acc[(mh_)*4 + m_][(nh_)*2 + n_] = \
            mfma16(af[m_][0], bf_[nh_][n_][0], acc[(mh_)*4 + m_][(nh_)*2 + n_]); \
        acc[(mh_)*4 + m_][(nh_)*2 + n_] = \
            mfma16(af[m_][1], bf_[nh_][n_][1], acc[(mh_)*4 + m_][(nh_)*2 + n_]); \
      } \
    __builtin_amdgcn_s_setprio(0); \
  } while (0)

  // ---- prologue: tile0 k0 fully, k1 first 3 half-tiles ----
  STAGE_A(tm, 0, 0); STAGE_B(tn, 0, 0); STAGE_B(tn, 0, 1); STAGE_A(tm, 0, 1);
  STAGE_A(tm, 1, 0); STAGE_B(tn, 1, 0); STAGE_B(tn, 1, 1);
  WAITVM(6);
  BAR();

#pragma unroll 1
  for (int r = 0; r < rounds; ++r) {
    const bool last = (r == rounds - 1);
    int tmn = tm, tnn = tn;
    if (!last) {
      int v = (int)blockIdx.x + (r + 1) * 256;
      int wg = (v & 7) * cpx + (v >> 3);
      tmn = (wg / nbx) << 8;
      tnn = (wg % nbx) << 8;
    }
    // ---- steady: K-tiles 0..13 (7 dual-iterations), stages within cur ----
#pragma unroll 1
    for (int T = 0; T < 14; T += 2) {
      LDA(0, 0); LDB(0, 0);
      STAGE_A(tm, T + 1, 1);
      BAR(); MM(0, 0); BAR();
      LDB(0, 1);
      STAGE_A(tm, T + 2, 0);
      BAR(); MM(0, 1); BAR();
      LDA(0, 1);
      STAGE_B(tn, T + 2, 0);
      BAR(); MM(1, 0); BAR();
      STAGE_B(tn, T + 2, 1);
      WAITVM(6);
      BAR(); MM(1, 1); BAR();
      LDA(1, 0); LDB(1, 0);
      STAGE_A(tm, T + 2, 1);
      BAR(); MM(0, 0); BAR();
      LDB(1, 1);
      STAGE_A(tm, T + 3, 0);
      BAR(); MM(0, 1); BAR();
      LDA(1, 1);
      STAGE_B(tn, T + 3, 0);
      BAR(); MM(1, 0); BAR();
      STAGE_B(tn, T + 3, 1);
      WAITVM(6);
      BAR(); MM(1, 1); BAR();
    }
    // ---- boundary: K-tiles 14,15; stage next tile's k0,k1 (or tail) ----
    if (!last) {
      LDA(0, 0); LDB(0, 0);
      STAGE_A(tm, 15, 1);
      BAR(); MM(0, 0); BAR();
      LDB(0, 1);
      STAGE_A(tmn, 0, 0);
      BAR(); MM(0, 1); BAR();
      LDA(0, 1);
      STAGE_B(tnn, 0, 0);
      BAR(); MM(1, 0); BAR();
      STAGE_B(tnn, 0, 1);
      WAITVM(6);
      BAR(); MM(1, 1); BAR();
      LDA(1, 0); LDB(1, 0);
      STAGE_A(tmn, 0, 1);
      BAR(); MM(0, 0); BAR();
      LDB(1, 1);
      STAGE_A(tmn, 1, 0);
      BAR(); MM(0, 1); BAR();
      LDA(1, 1);
      STAGE_B(tnn, 1, 0);
      BAR(); MM(1, 0); BAR();
      STAGE_B(tnn, 1, 1);
      WAITVM(6);
      BAR(); MM(1, 1); BAR();
    } else {
      LDA(0, 0); LDB(0, 0);
      STAGE_A(tm, 15, 1);
      BAR(); MM(0, 0); BAR();
      LDB(0, 1);
      BAR(); MM(0, 1); BAR();
      LDA(0, 1);
      BAR(); MM(1, 0); BAR();
      WAITVM(0);
      BAR(); MM(1, 1); BAR();
      LDA(1, 0); LDB(1, 0);
      BAR(); MM(0, 0); BAR();
      LDB(1, 1);
      BAR(); MM(0, 1); BAR();
      LDA(1, 1);
      BAR(); MM(1, 0); BAR();
      BAR(); MM(1, 1); BAR();
    }
    // ---- epilogue for cur tile (stores fire-and-forget, overlap next) ----
#pragma unroll
    for (int mh = 0; mh < 2; ++mh)
#pragma unroll
      for (int m = 0; m < 4; ++m)
#pragma unroll
        for (int nh = 0; nh < 2; ++nh)
#pragma unroll
          for (int n = 0; n < 2; ++n)
#pragma unroll
            for (int j = 0; j < 4; ++j) {
              int row = tm + mh * 128 + wr * 64 + m * 16 + q * 4 + j;
              int col = tn + nh * 128 + wc * 32 + n * 16 + lr;
              float v = acc[mh * 4 + m][nh * 2 + n][j];
              if constexpr (sizeof(OutT) == 2)
                C[(size_t)row * N + col] = (OutT)f2b(v);
              else
                C[(size_t)row * N + col] = v;
            }
#pragma unroll
    for (int i = 0; i < 8; ++i)
#pragma unroll
      for (int jj = 0; jj < 4; ++jj) acc[i][jj] = (f32x4){0.f, 0.f, 0.f, 0.f};
    tm = tmn;
    tn = tnn;
  }
#undef STAGE_A
#undef STAGE_B
#undef LDA
#undef LDB
#undef MM
}

// ---------------- per-token 16-head attention over head axis ----------------
__global__ __launch_bounds__(256, 4) void attn16(
    const unsigned short* __restrict__ qkv, unsigned short* __restrict__ out) {
  __shared__ unsigned short P[4][16 * 16];
  const int t = threadIdx.x, w = t >> 6, l = t & 63;
  const int tok = blockIdx.x * 4 + w;
  const unsigned short* q = qkv + (size_t)tok * 3072;
  const unsigned short* kp = q + 1024;
  const unsigned short* vp = q + 2048;
  const int lr = l & 15, lk = (l >> 4) * 8;
  bf16x8 aq0 = *reinterpret_cast<const bf16x8*>(q + lr * 64 + lk);
  bf16x8 aq1 = *reinterpret_cast<const bf16x8*>(q + lr * 64 + 32 + lk);
  bf16x8 bk0 = *reinterpret_cast<const bf16x8*>(kp + lr * 64 + lk);
  bf16x8 bk1 = *reinterpret_cast<const bf16x8*>(kp + lr * 64 + 32 + lk);
  f32x4 s = {};
  s = mfma16(aq0, bk0, s);
  s = mfma16(aq1, bk1, s);
  const float cexp = 0.125f * 1.44269504f;
  float p[4];
#pragma unroll
  for (int j = 0; j < 4; ++j) {
    float m = s[j];
    m = fmaxf(m, __shfl_xor(m, 1));
    m = fmaxf(m, __shfl_xor(m, 2));
    m = fmaxf(m, __shfl_xor(m, 4));
    m = fmaxf(m, __shfl_xor(m, 8));
    float e = exp2f((s[j] - m) * cexp);
    float sum = e;
    sum += __shfl_xor(sum, 1);
    sum += __shfl_xor(sum, 2);
    sum += __shfl_xor(sum, 4);
    sum += __shfl_xor(sum, 8);
    p[j] = e / sum;
  }
  unsigned short* Pw = P[w];
#pragma unroll
  for (int j = 0; j < 4; ++j) Pw[((l >> 4) * 4 + j) * 16 + lr] = f2b(p[j]);
  WAITLGKM0();
  ushort8 zz = {0, 0, 0, 0, 0, 0, 0, 0};
  bf16x8 ap = __builtin_bit_cast(bf16x8, zz);
  bf16x8 bv[4];
#pragma unroll
  for (int b = 0; b < 4; ++b) bv[b] = ap;
  if (l < 32) {
    ap = *reinterpret_cast<const bf16x8*>(&Pw[lr * 16 + lk]);
#pragma unroll
    for (int b = 0; b < 4; ++b) {
      ushort8 tmp;
#pragma unroll
      for (int j = 0; j < 8; ++j) tmp[j] = vp[(lk + j) * 64 + b * 16 + lr];
      bv[b] = __builtin_bit_cast(bf16x8, tmp);
    }
  }
  f32x4 o[4] = {};
#pragma unroll
  for (int b = 0; b < 4; ++b) o[b] = mfma16(ap, bv[b], o[b]);
  unsigned short* op = out + (size_t)tok * 1024;
#pragma unroll
  for (int b = 0; b < 4; ++b)
#pragma unroll
    for (int j = 0; j < 4; ++j)
      op[((l >> 4) * 4 + j) * 64 + b * 16 + lr] = f2b(o[b][j]);
}

// ---------------------------------------------------------------------------
extern "C" void kernel_launch(void* const* d_in, const int* in_sizes, int n_in,
                              void* d_out, int out_size, void* d_ws, size_t ws_size,
                              hipStream_t stream) {
  const float* x = (const float*)d_in[0];
  const float* Wq = (const float*)d_in[1];
  const float* Wk = (const float*)d_in[2];
  const float* Wv = (const float*)d_in[3];
  const float* Wo = (const float*)d_in[4];

  unsigned short* xb = (unsigned short*)d_ws;            // 64M elems (128 MB)
  unsigned short* wqkv = xb + (size_t)NTOK * E;          // 3M (6 MB)
  unsigned short* wo = wqkv + (size_t)3 * E * E;         // 1M (2 MB)
  unsigned short* qkv = wo + (size_t)E * E;              // 192M (384 MB)
  unsigned short* att = qkv + (size_t)NTOK * 3 * E;      // 64M (128 MB)

  cvt8<<<(NTOK * E / 8) / 256, 256, 0, stream>>>(x, xb, NTOK * E / 8);
  cvtW<<<(4 * E * E / 8) / 256, 256, 0, stream>>>(Wq, Wk, Wv, Wo, wqkv);

  // QKV: [65536,1024] x [3072,1024]^T -> [65536,3072]; 3072 tiles, 12 rounds
  gemmp<unsigned short><<<256, 512, 0, stream>>>(xb, wqkv, qkv, 3 * E, 12, 12);

  attn16<<<NTOK / 4, 256, 0, stream>>>(qkv, att);

  // O-proj: [65536,1024] x [1024,1024]^T -> fp32; 1024 tiles, 4 rounds
  gemmp<float><<<256, 512, 0, stream>>>(att, wo, (float*)d_out, E, 4, 4);
}

// Round 6
// 814.223 us; speedup vs baseline: 1.5694x; 1.5694x over previous
//
#include <hip/hip_runtime.h>
#include <hip/hip_bf16.h>
#include <cstdint>

#define DEV static __device__ __forceinline__

typedef __attribute__((ext_vector_type(8))) __bf16 bf16x8;
typedef __attribute__((ext_vector_type(4))) float f32x4;
typedef __attribute__((ext_vector_type(16))) float f32x16;
typedef __attribute__((ext_vector_type(8))) unsigned short ushort8;

constexpr int NTOK = 65536;
constexpr int E = 1024;

DEV unsigned short f2b(float f) {
  unsigned int u = __builtin_bit_cast(unsigned int, f);
  u += 0x7fffu + ((u >> 16) & 1u);
  return (unsigned short)(u >> 16);
}

DEV f32x4 mfma16(bf16x8 a, bf16x8 b, f32x4 c) {
  return __builtin_amdgcn_mfma_f32_16x16x32_bf16(a, b, c, 0, 0, 0);
}

DEV f32x16 mfma32(bf16x8 a, bf16x8 b, f32x16 c) {
  return __builtin_amdgcn_mfma_f32_32x32x16_bf16(a, b, c, 0, 0, 0);
}

DEV void gload16(const void* g, const void* l) {
  __builtin_amdgcn_global_load_lds(
      (const __attribute__((address_space(1))) void*)g,
      (__attribute__((address_space(3))) void*)l, 16, 0, 0);
}

DEV void BAR() {
  asm volatile("" ::: "memory");
  __builtin_amdgcn_s_barrier();
  asm volatile("" ::: "memory");
  __builtin_amdgcn_sched_barrier(0);
}

#define WAITVM(n_) do { \
  asm volatile("s_waitcnt vmcnt(" #n_ ")" ::: "memory"); \
  __builtin_amdgcn_sched_barrier(0); \
} while (0)

#define WAITLGKM0() do { \
  asm volatile("s_waitcnt lgkmcnt(0)" ::: "memory"); \
  __builtin_amdgcn_sched_barrier(0); \
} while (0)

// ---------------- fp32 -> bf16 converts ----------------
__global__ void cvt8(const float* __restrict__ in, unsigned short* __restrict__ out,
                     int n8) {
  int i = blockIdx.x * blockDim.x + threadIdx.x;
  if (i >= n8) return;
  const float4* p = (const float4*)(in + (size_t)i * 8);
  float4 a = p[0], b = p[1];
  ushort8 r;
  r[0] = f2b(a.x); r[1] = f2b(a.y); r[2] = f2b(a.z); r[3] = f2b(a.w);
  r[4] = f2b(b.x); r[5] = f2b(b.y); r[6] = f2b(b.z); r[7] = f2b(b.w);
  *(ushort8*)(out + (size_t)i * 8) = r;
}

__global__ void cvtW(const float* __restrict__ Wq, const float* __restrict__ Wk,
                     const float* __restrict__ Wv, const float* __restrict__ Wo,
                     unsigned short* __restrict__ out) {
  int i = blockIdx.x * blockDim.x + threadIdx.x;  // 0..524287
  int wsel = i >> 17;
  const float* src = wsel == 0 ? Wq : wsel == 1 ? Wk : wsel == 2 ? Wv : Wo;
  int j = i & 131071;
  const float4* p = (const float4*)(src + (size_t)j * 8);
  float4 a = p[0], b = p[1];
  ushort8 r;
  r[0] = f2b(a.x); r[1] = f2b(a.y); r[2] = f2b(a.z); r[3] = f2b(a.w);
  r[4] = f2b(b.x); r[5] = f2b(b.y); r[6] = f2b(b.z); r[7] = f2b(b.w);
  *(ushort8*)(out + (size_t)i * 8) = r;
}

// ---------------------------------------------------------------------------
// 256x256-tile, BK=64, 8-wave (2Mx4N), 8 phases / 2 K-tiles, 32x32x16 MFMA.
// R3's proven schedule and region lifetimes kept VERBATIM: mh/nh index LDS
// HALVES (all waves read half mh/nh in a phase), so A-h0 is read only @ph1,
// A-h1 @ph3, B-h0 @ph1, B-h1 @ph2 — staging A-h0@ph2/B-h0@ph3/B-h1@ph4/
// A-h1@ph5 never overwrites a live region.
// Per quadrant (mh,nh): wave computes rows mh*128+wr*64+{0,32} x cols
// nh*128+wc*32 via 8 mfma32 (i x ks).
// T1 XCD swizzle, T2 st-swizzle, T3/T4 counted vmcnt(6), T5 setprio.
// LDS 128 KiB: A[2buf][2half][128][64]bf16 @0, B same @65536. K%128==0.
// ---------------------------------------------------------------------------
template <typename OutT>
__global__ __launch_bounds__(512, 2) void gemm8(
    const unsigned short* __restrict__ A, const unsigned short* __restrict__ B,
    OutT* __restrict__ C, int M, int N, int K, int nbx) {
  __shared__ char smem[131072];
  char* sA = smem;
  char* sB = smem + 65536;

  const int NT = K >> 6;
  const int nwg = gridDim.x;
  const int cpx = nwg >> 3;
  const int wg = ((int)blockIdx.x & 7) * cpx + ((int)blockIdx.x >> 3);
  const int tm = (wg / nbx) * 256;
  const int tn = (wg % nbx) * 256;

  const int t = threadIdx.x;
  const int w = t >> 6, l = t & 63;
  const int wr = w >> 2, wc = w & 3;  // 2 x 4 wave grid
  const int arL = l & 31;             // row (A) / col (B) within 32-block
  const int kh = (l >> 5) * 16;       // k-half byte offset (8 bf16)

  // staging lane constants (source column pre-swizzled: slot ^ (row&7))
  const int srow = w * 8 + (l >> 3);
  const int scol = ((l & 7) ^ (l >> 3)) * 8;
  // ds_read swizzle: slot = chunk ^ (row&7); row&7 == l&7 for all our reads
  const int xorv = (l & 7) << 4;
  const int aRB = wr * 8192 + arL * 128;  // 64-row group wr, row arL
  const int bRB = wc * 4096 + arL * 128;  // 32-col group wc, col arL

#define STAGE_A(tt_, h_) do { \
    const unsigned short* g_ = A + (size_t)(tm + (h_)*128 + srow) * K + (tt_)*64 + scol; \
    const char* d_ = sA + (((tt_) & 1) * 32768 + (h_)*16384 + w * 1024); \
    gload16(g_, d_); \
    gload16(g_ + (size_t)64 * K, d_ + 8192); \
  } while (0)

#define STAGE_B(tt_, h_) do { \
    const unsigned short* g_ = B + (size_t)(tn + (h_)*128 + srow) * K + (tt_)*64 + scol; \
    const char* d_ = sB + (((tt_) & 1) * 32768 + (h_)*16384 + w * 1024); \
    gload16(g_, d_); \
    gload16(g_ + (size_t)64 * K, d_ + 8192); \
  } while (0)

  f32x16 acc[4][2] = {};  // [mh*2+i][nh]: 32-row block x 32-col block
  bf16x8 af[2][4];        // [i][ks] for current mh
  bf16x8 bB[2][4];        // [nh][ks], both halves persist in registers

#define LDA(buf_, mh_) do { \
    _Pragma("unroll") for (int i_ = 0; i_ < 2; ++i_) \
      _Pragma("unroll") for (int ks_ = 0; ks_ < 4; ++ks_) \
        af[i_][ks_] = *(const bf16x8*)(sA + (buf_)*32768 + (mh_)*16384 + aRB + \
                                       i_*4096 + ((ks_*32 + kh) ^ xorv)); \
  } while (0)

#define LDB(buf_, nh_) do { \
    _Pragma("unroll") for (int ks_ = 0; ks_ < 4; ++ks_) \
      bB[nh_][ks_] = *(const bf16x8*)(sB + (buf_)*32768 + (nh_)*16384 + bRB + \
                                      ((ks_*32 + kh) ^ xorv)); \
  } while (0)

#define MM(mh_, nh_) do { \
    __builtin_amdgcn_s_setprio(1); \
    _Pragma("unroll") for (int ks_ = 0; ks_ < 4; ++ks_) \
      _Pragma("unroll") for (int i_ = 0; i_ < 2; ++i_) \
        acc[(mh_)*2 + i_][nh_] = \
            mfma32(af[i_][ks_], bB[nh_][ks_], acc[(mh_)*2 + i_][nh_]); \
    __builtin_amdgcn_s_setprio(0); \
  } while (0)

  // ---- prologue: tile0 fully, tile1 first 3 half-tiles; drain tile0 ----
  STAGE_A(0, 0); STAGE_B(0, 0); STAGE_B(0, 1); STAGE_A(0, 1);
  STAGE_A(1, 0); STAGE_B(1, 0); STAGE_B(1, 1);
  WAITVM(6);
  BAR();

  int T = 0;
  // ---- steady state: branch-free, 2 K-tiles per iteration ----
  for (; T + 3 < NT; T += 2) {
    LDA(0, 0); LDB(0, 0);
    STAGE_A(T + 1, 1);
    BAR(); MM(0, 0); BAR();
    LDB(0, 1);
    STAGE_A(T + 2, 0);
    BAR(); MM(0, 1); BAR();
    LDA(0, 1);
    STAGE_B(T + 2, 0);
    BAR(); MM(1, 0); BAR();
    STAGE_B(T + 2, 1);
    WAITVM(6);
    BAR(); MM(1, 1); BAR();
    LDA(1, 0); LDB(1, 0);
    STAGE_A(T + 2, 1);
    BAR(); MM(0, 0); BAR();
    LDB(1, 1);
    STAGE_A(T + 3, 0);
    BAR(); MM(0, 1); BAR();
    LDA(1, 1);
    STAGE_B(T + 3, 0);
    BAR(); MM(1, 0); BAR();
    STAGE_B(T + 3, 1);
    WAITVM(6);
    BAR(); MM(1, 1); BAR();
  }
  // ---- tail: last 2 tiles ----
  {
    LDA(0, 0); LDB(0, 0);
    STAGE_A(T + 1, 1);
    BAR(); MM(0, 0); BAR();
    LDB(0, 1);
    BAR(); MM(0, 1); BAR();
    LDA(0, 1);
    BAR(); MM(1, 0); BAR();
    WAITVM(0);
    BAR(); MM(1, 1); BAR();
    LDA(1, 0); LDB(1, 0);
    BAR(); MM(0, 0); BAR();
    LDB(1, 1);
    BAR(); MM(0, 1); BAR();
    LDA(1, 1);
    BAR(); MM(1, 0); BAR();
    BAR(); MM(1, 1); BAR();
  }

  // ---- epilogue: 32x32 C/D: col=lane&31, row=(j&3)+8*(j>>2)+4*(l>>5) ----
#pragma unroll
  for (int mh = 0; mh < 2; ++mh)
#pragma unroll
    for (int i = 0; i < 2; ++i)
#pragma unroll
      for (int nh = 0; nh < 2; ++nh)
#pragma unroll
        for (int j = 0; j < 16; ++j) {
          int row = tm + mh * 128 + wr * 64 + i * 32 + (l >> 5) * 4 + (j & 3) + 8 * (j >> 2);
          int col = tn + nh * 128 + wc * 32 + arL;
          float v = acc[mh * 2 + i][nh][j];
          if constexpr (sizeof(OutT) == 2)
            C[(size_t)row * N + col] = (OutT)f2b(v);
          else
            C[(size_t)row * N + col] = v;
        }
#undef STAGE_A
#undef STAGE_B
#undef LDA
#undef LDB
#undef MM
}

// ---------------- per-token 16-head attention over head axis ----------------
__global__ __launch_bounds__(256, 4) void attn16(
    const unsigned short* __restrict__ qkv, unsigned short* __restrict__ out) {
  __shared__ unsigned short P[4][16 * 16];
  const int t = threadIdx.x, w = t >> 6, l = t & 63;
  const int tok = blockIdx.x * 4 + w;
  const unsigned short* q = qkv + (size_t)tok * 3072;
  const unsigned short* kp = q + 1024;
  const unsigned short* vp = q + 2048;
  const int lr = l & 15, lk = (l >> 4) * 8;
  bf16x8 aq0 = *reinterpret_cast<const bf16x8*>(q + lr * 64 + lk);
  bf16x8 aq1 = *reinterpret_cast<const bf16x8*>(q + lr * 64 + 32 + lk);
  bf16x8 bk0 = *reinterpret_cast<const bf16x8*>(kp + lr * 64 + lk);
  bf16x8 bk1 = *reinterpret_cast<const bf16x8*>(kp + lr * 64 + 32 + lk);
  f32x4 s = {};
  s = mfma16(aq0, bk0, s);
  s = mfma16(aq1, bk1, s);
  const float cexp = 0.125f * 1.44269504f;
  float p[4];
#pragma unroll
  for (int j = 0; j < 4; ++j) {
    float m = s[j];
    m = fmaxf(m, __shfl_xor(m, 1));
    m = fmaxf(m, __shfl_xor(m, 2));
    m = fmaxf(m, __shfl_xor(m, 4));
    m = fmaxf(m, __shfl_xor(m, 8));
    float e = exp2f((s[j] - m) * cexp);
    float sum = e;
    sum += __shfl_xor(sum, 1);
    sum += __shfl_xor(sum, 2);
    sum += __shfl_xor(sum, 4);
    sum += __shfl_xor(sum, 8);
    p[j] = e / sum;
  }
  unsigned short* Pw = P[w];
#pragma unroll
  for (int j = 0; j < 4; ++j) Pw[((l >> 4) * 4 + j) * 16 + lr] = f2b(p[j]);
  WAITLGKM0();
  ushort8 zz = {0, 0, 0, 0, 0, 0, 0, 0};
  bf16x8 ap = __builtin_bit_cast(bf16x8, zz);
  bf16x8 bv[4];
#pragma unroll
  for (int b = 0; b < 4; ++b) bv[b] = ap;
  if (l < 32) {
    ap = *reinterpret_cast<const bf16x8*>(&Pw[lr * 16 + lk]);
#pragma unroll
    for (int b = 0; b < 4; ++b) {
      ushort8 tmp;
#pragma unroll
      for (int j = 0; j < 8; ++j) tmp[j] = vp[(lk + j) * 64 + b * 16 + lr];
      bv[b] = __builtin_bit_cast(bf16x8, tmp);
    }
  }
  f32x4 o[4] = {};
#pragma unroll
  for (int b = 0; b < 4; ++b) o[b] = mfma16(ap, bv[b], o[b]);
  unsigned short* op = out + (size_t)tok * 1024;
#pragma unroll
  for (int b = 0; b < 4; ++b)
#pragma unroll
    for (int j = 0; j < 4; ++j)
      op[((l >> 4) * 4 + j) * 64 + b * 16 + lr] = f2b(o[b][j]);
}

// ---------------------------------------------------------------------------
extern "C" void kernel_launch(void* const* d_in, const int* in_sizes, int n_in,
                              void* d_out, int out_size, void* d_ws, size_t ws_size,
                              hipStream_t stream) {
  const float* x = (const float*)d_in[0];
  const float* Wq = (const float*)d_in[1];
  const float* Wk = (const float*)d_in[2];
  const float* Wv = (const float*)d_in[3];
  const float* Wo = (const float*)d_in[4];

  unsigned short* xb = (unsigned short*)d_ws;            // 64M elems (128 MB)
  unsigned short* wqkv = xb + (size_t)NTOK * E;          // 3M (6 MB)
  unsigned short* wo = wqkv + (size_t)3 * E * E;         // 1M (2 MB)
  unsigned short* qkv = wo + (size_t)E * E;              // 192M (384 MB)
  unsigned short* att = qkv + (size_t)NTOK * 3 * E;      // 64M (128 MB)

  cvt8<<<(NTOK * E / 8) / 256, 256, 0, stream>>>(x, xb, NTOK * E / 8);
  cvtW<<<(4 * E * E / 8) / 256, 256, 0, stream>>>(Wq, Wk, Wv, Wo, wqkv);

  // QKV: [65536,1024] x [3072,1024]^T -> [65536,3072]
  gemm8<unsigned short><<<(NTOK / 256) * (3 * E / 256), 512, 0, stream>>>(
      xb, wqkv, qkv, NTOK, 3 * E, E, 3 * E / 256);

  attn16<<<NTOK / 4, 256, 0, stream>>>(qkv, att);

  // O-proj: [65536,1024] x [1024,1024]^T -> fp32
  gemm8<float><<<(NTOK / 256) * (E / 256), 512, 0, stream>>>(
      att, wo, (float*)d_out, NTOK, E, E, E / 256);
}

// Round 8
// 740.529 us; speedup vs baseline: 1.7256x; 1.0995x over previous
//
#include <hip/hip_runtime.h>
#include <hip/hip_bf16.h>
#include <cstdint>

#define DEV static __device__ __forceinline__

typedef __attribute__((ext_vector_type(8))) __bf16 bf16x8;
typedef __attribute__((ext_vector_type(4))) float f32x4;
typedef __attribute__((ext_vector_type(8))) unsigned short ushort8;

constexpr int NTOK = 65536;
constexpr int E = 1024;

DEV unsigned short f2b(float f) {
  unsigned int u = __builtin_bit_cast(unsigned int, f);
  u += 0x7fffu + ((u >> 16) & 1u);
  return (unsigned short)(u >> 16);
}

DEV f32x4 mfma16(bf16x8 a, bf16x8 b, f32x4 c) {
  return __builtin_amdgcn_mfma_f32_16x16x32_bf16(a, b, c, 0, 0, 0);
}

DEV void gload16(const void* g, const void* l) {
  __builtin_amdgcn_global_load_lds(
      (const __attribute__((address_space(1))) void*)g,
      (__attribute__((address_space(3))) void*)l, 16, 0, 0);
}

DEV void BAR() {
  asm volatile("" ::: "memory");
  __builtin_amdgcn_s_barrier();
  asm volatile("" ::: "memory");
  __builtin_amdgcn_sched_barrier(0);
}

#define WAITVM(n_) do { \
  asm volatile("s_waitcnt vmcnt(" #n_ ")" ::: "memory"); \
  __builtin_amdgcn_sched_barrier(0); \
} while (0)

// ---------------- fp32 -> bf16 converts ----------------
__global__ void cvt8(const float* __restrict__ in, unsigned short* __restrict__ out,
                     int n8) {
  int i = blockIdx.x * blockDim.x + threadIdx.x;
  if (i >= n8) return;
  const float4* p = (const float4*)(in + (size_t)i * 8);
  float4 a = p[0], b = p[1];
  ushort8 r;
  r[0] = f2b(a.x); r[1] = f2b(a.y); r[2] = f2b(a.z); r[3] = f2b(a.w);
  r[4] = f2b(b.x); r[5] = f2b(b.y); r[6] = f2b(b.z); r[7] = f2b(b.w);
  *(ushort8*)(out + (size_t)i * 8) = r;
}

__global__ void cvtW(const float* __restrict__ Wq, const float* __restrict__ Wk,
                     const float* __restrict__ Wv, const float* __restrict__ Wo,
                     unsigned short* __restrict__ out) {
  int i = blockIdx.x * blockDim.x + threadIdx.x;  // 0..524287
  int wsel = i >> 17;
  const float* src = wsel == 0 ? Wq : wsel == 1 ? Wk : wsel == 2 ? Wv : Wo;
  int j = i & 131071;
  const float4* p = (const float4*)(src + (size_t)j * 8);
  float4 a = p[0], b = p[1];
  ushort8 r;
  r[0] = f2b(a.x); r[1] = f2b(a.y); r[2] = f2b(a.z); r[3] = f2b(a.w);
  r[4] = f2b(b.x); r[5] = f2b(b.y); r[6] = f2b(b.z); r[7] = f2b(b.w);
  *(ushort8*)(out + (size_t)i * 8) = r;
}

// ---------------------------------------------------------------------------
// R3-PROVEN GEMM (verbatim): 256x256-tile, BK=64, 8-wave (2Mx4N), 8 phases /
// 2 K-tiles with compile-time LDS offsets. T1 XCD swizzle, T2 st-swizzle
// (pre-swizzled global source + XOR'd ds_read), T3/T4 counted vmcnt(6),
// T5 setprio. LDS 128 KiB. Requires K % 128 == 0.
// ---------------------------------------------------------------------------
template <typename OutT>
__global__ __launch_bounds__(512, 2) void gemm8(
    const unsigned short* __restrict__ A, const unsigned short* __restrict__ B,
    OutT* __restrict__ C, int M, int N, int K, int nbx) {
  __shared__ char smem[131072];
  char* sA = smem;
  char* sB = smem + 65536;

  const int NT = K >> 6;
  const int nwg = gridDim.x;
  const int cpx = nwg >> 3;
  const int wg = ((int)blockIdx.x & 7) * cpx + ((int)blockIdx.x >> 3);
  const int tm = (wg / nbx) * 256;
  const int tn = (wg % nbx) * 256;

  const int t = threadIdx.x;
  const int w = t >> 6, l = t & 63;
  const int wr = w >> 2, wc = w & 3;  // 2 x 4 wave grid
  const int lr = l & 15, q = l >> 4;

  const int srow = w * 8 + (l >> 3);
  const int scol = ((l & 7) ^ (l >> 3)) * 8;
  const int xorv = (lr & 7) << 4;
  const int offk0 = (q * 16) ^ xorv;
  const int offk1 = (64 + q * 16) ^ xorv;
  const int aRB = wr * 8192 + lr * 128;
  const int bRB = wc * 4096 + lr * 128;

#define STAGE_A(tt_, h_) do { \
    const unsigned short* g_ = A + (size_t)(tm + (h_)*128 + srow) * K + (tt_)*64 + scol; \
    const char* d_ = sA + (((tt_) & 1) * 32768 + (h_)*16384 + w * 1024); \
    gload16(g_, d_); \
    gload16(g_ + (size_t)64 * K, d_ + 8192); \
  } while (0)

#define STAGE_B(tt_, h_) do { \
    const unsigned short* g_ = B + (size_t)(tn + (h_)*128 + srow) * K + (tt_)*64 + scol; \
    const char* d_ = sB + (((tt_) & 1) * 32768 + (h_)*16384 + w * 1024); \
    gload16(g_, d_); \
    gload16(g_ + (size_t)64 * K, d_ + 8192); \
  } while (0)

  f32x4 acc[8][4] = {};
  bf16x8 af[4][2];
  bf16x8 bf_[2][2][2];

#define LDA(buf_, mh_) do { \
    _Pragma("unroll") for (int m_ = 0; m_ < 4; ++m_) { \
      af[m_][0] = *(const bf16x8*)(sA + (buf_)*32768 + (mh_)*16384 + m_*2048 + aRB + offk0); \
      af[m_][1] = *(const bf16x8*)(sA + (buf_)*32768 + (mh_)*16384 + m_*2048 + aRB + offk1); \
    } \
  } while (0)

#define LDB(buf_, nh_) do { \
    _Pragma("unroll") for (int n_ = 0; n_ < 2; ++n_) { \
      bf_[nh_][n_][0] = *(const bf16x8*)(sB + (buf_)*32768 + (nh_)*16384 + n_*2048 + bRB + offk0); \
      bf_[nh_][n_][1] = *(const bf16x8*)(sB + (buf_)*32768 + (nh_)*16384 + n_*2048 + bRB + offk1); \
    } \
  } while (0)

#define MM(mh_, nh_) do { \
    __builtin_amdgcn_s_setprio(1); \
    _Pragma("unroll") for (int m_ = 0; m_ < 4; ++m_) \
      _Pragma("unroll") for (int n_ = 0; n_ < 2; ++n_) { \
        acc[(mh_)*4 + m_][(nh_)*2 + n_] = \
            mfma16(af[m_][0], bf_[nh_][n_][0], acc[(mh_)*4 + m_][(nh_)*2 + n_]); \
        acc[(mh_)*4 + m_][(nh_)*2 + n_] = \
            mfma16(af[m_][1], bf_[nh_][n_][1], acc[(mh_)*4 + m_][(nh_)*2 + n_]); \
      } \
    __builtin_amdgcn_s_setprio(0); \
  } while (0)

  // ---- prologue: tile0 fully, tile1 first 3 half-tiles; drain tile0 ----
  STAGE_A(0, 0); STAGE_B(0, 0); STAGE_B(0, 1); STAGE_A(0, 1);
  STAGE_A(1, 0); STAGE_B(1, 0); STAGE_B(1, 1);
  WAITVM(6);
  BAR();

  int T = 0;
  for (; T + 3 < NT; T += 2) {
    LDA(0, 0); LDB(0, 0);
    STAGE_A(T + 1, 1);
    BAR(); MM(0, 0); BAR();
    LDB(0, 1);
    STAGE_A(T + 2, 0);
    BAR(); MM(0, 1); BAR();
    LDA(0, 1);
    STAGE_B(T + 2, 0);
    BAR(); MM(1, 0); BAR();
    STAGE_B(T + 2, 1);
    WAITVM(6);
    BAR(); MM(1, 1); BAR();
    LDA(1, 0); LDB(1, 0);
    STAGE_A(T + 2, 1);
    BAR(); MM(0, 0); BAR();
    LDB(1, 1);
    STAGE_A(T + 3, 0);
    BAR(); MM(0, 1); BAR();
    LDA(1, 1);
    STAGE_B(T + 3, 0);
    BAR(); MM(1, 0); BAR();
    STAGE_B(T + 3, 1);
    WAITVM(6);
    BAR(); MM(1, 1); BAR();
  }
  {
    LDA(0, 0); LDB(0, 0);
    STAGE_A(T + 1, 1);
    BAR(); MM(0, 0); BAR();
    LDB(0, 1);
    BAR(); MM(0, 1); BAR();
    LDA(0, 1);
    BAR(); MM(1, 0); BAR();
    WAITVM(0);
    BAR(); MM(1, 1); BAR();
    LDA(1, 0); LDB(1, 0);
    BAR(); MM(0, 0); BAR();
    LDB(1, 1);
    BAR(); MM(0, 1); BAR();
    LDA(1, 1);
    BAR(); MM(1, 0); BAR();
    BAR(); MM(1, 1); BAR();
  }

#pragma unroll
  for (int mh = 0; mh < 2; ++mh)
#pragma unroll
    for (int m = 0; m < 4; ++m)
#pragma unroll
      for (int nh = 0; nh < 2; ++nh)
#pragma unroll
        for (int n = 0; n < 2; ++n)
#pragma unroll
          for (int j = 0; j < 4; ++j) {
            int row = tm + mh * 128 + wr * 64 + m * 16 + q * 4 + j;
            int col = tn + nh * 128 + wc * 32 + n * 16 + lr;
            float v = acc[mh * 4 + m][nh * 2 + n][j];
            if constexpr (sizeof(OutT) == 2)
              C[(size_t)row * N + col] = (OutT)f2b(v);
            else
              C[(size_t)row * N + col] = v;
          }
#undef STAGE_A
#undef STAGE_B
#undef LDA
#undef LDB
#undef MM
}

// ---------------- per-token 16-head attention over head axis ----------------
// 1 wave/token. SWAPPED QK^T: s = mfma(K,Q) -> s[j] = S[g=(l>>4)*4+j][h=l&15].
// Softmax over g: in-register over j + shfl_xor(16,32). PV A-fragment
// P[h=l&15][g=(l>>4)*8+jj] gathered via 8 shuffles (zero for l>=32, since
// A rows k>=16 are structurally zero). V loads / PV MFMA / stores identical
// to the proven R6 kernel. No LDS.
__global__ __launch_bounds__(256, 4) void attn16(
    const unsigned short* __restrict__ qkv, unsigned short* __restrict__ out) {
  const int t = threadIdx.x, w = t >> 6, l = t & 63;
  const int tok = blockIdx.x * 4 + w;
  const unsigned short* q = qkv + (size_t)tok * 3072;
  const unsigned short* kp = q + 1024;
  const unsigned short* vp = q + 2048;
  const int lr = l & 15, lk = (l >> 4) * 8;

  bf16x8 aq0 = *reinterpret_cast<const bf16x8*>(q + lr * 64 + lk);
  bf16x8 aq1 = *reinterpret_cast<const bf16x8*>(q + lr * 64 + 32 + lk);
  bf16x8 bk0 = *reinterpret_cast<const bf16x8*>(kp + lr * 64 + lk);
  bf16x8 bk1 = *reinterpret_cast<const bf16x8*>(kp + lr * 64 + 32 + lk);
  f32x4 s = {};
  s = mfma16(bk0, aq0, s);  // swapped: S^T
  s = mfma16(bk1, aq1, s);

  // softmax over g (spread over j in-register x lane-groups 16,32)
  const float cexp = 0.125f * 1.44269504f;
  float mx = fmaxf(fmaxf(s[0], s[1]), fmaxf(s[2], s[3]));
  mx = fmaxf(mx, __shfl_xor(mx, 16));
  mx = fmaxf(mx, __shfl_xor(mx, 32));
  float e0 = exp2f((s[0] - mx) * cexp);
  float e1 = exp2f((s[1] - mx) * cexp);
  float e2 = exp2f((s[2] - mx) * cexp);
  float e3 = exp2f((s[3] - mx) * cexp);
  float sm = (e0 + e1) + (e2 + e3);
  sm += __shfl_xor(sm, 16);
  sm += __shfl_xor(sm, 32);
  float inv = 1.0f / sm;
  float p[4] = {e0 * inv, e1 * inv, e2 * inv, e3 * inv};

  // gather PV A-fragment: av[jj] = P[h=lr][g=(l>>4)*8+jj] for l<32, else 0
  ushort8 au;
#pragma unroll
  for (int jj = 0; jj < 8; ++jj) {
    int src = (lr + (l >> 4) * 32 + (jj >> 2) * 16) & 63;
    float v = __shfl(p[jj & 3], src);
    au[jj] = (l < 32) ? f2b(v) : (unsigned short)0;
  }
  bf16x8 ap = __builtin_bit_cast(bf16x8, au);

  // V B-fragments (proven): lanes<32 load, upper half zero (A rows k>=16 = 0)
  ushort8 zz = {0, 0, 0, 0, 0, 0, 0, 0};
  bf16x8 bv[4];
#pragma unroll
  for (int b = 0; b < 4; ++b) bv[b] = __builtin_bit_cast(bf16x8, zz);
  if (l < 32) {
#pragma unroll
    for (int b = 0; b < 4; ++b) {
      ushort8 tmp;
#pragma unroll
      for (int j = 0; j < 8; ++j) tmp[j] = vp[(lk + j) * 64 + b * 16 + lr];
      bv[b] = __builtin_bit_cast(bf16x8, tmp);
    }
  }

  f32x4 o[4] = {};
#pragma unroll
  for (int b = 0; b < 4; ++b) o[b] = mfma16(ap, bv[b], o[b]);

  unsigned short* op = out + (size_t)tok * 1024;
#pragma unroll
  for (int b = 0; b < 4; ++b)
#pragma unroll
    for (int j = 0; j < 4; ++j)
      op[((l >> 4) * 4 + j) * 64 + b * 16 + lr] = f2b(o[b][j]);
}

// ---------------------------------------------------------------------------
extern "C" void kernel_launch(void* const* d_in, const int* in_sizes, int n_in,
                              void* d_out, int out_size, void* d_ws, size_t ws_size,
                              hipStream_t stream) {
  const float* x = (const float*)d_in[0];
  const float* Wq = (const float*)d_in[1];
  const float* Wk = (const float*)d_in[2];
  const float* Wv = (const float*)d_in[3];
  const float* Wo = (const float*)d_in[4];

  unsigned short* xb = (unsigned short*)d_ws;            // 64M elems (128 MB)
  unsigned short* wqkv = xb + (size_t)NTOK * E;          // 3M (6 MB)
  unsigned short* wo = wqkv + (size_t)3 * E * E;         // 1M (2 MB)
  unsigned short* qkv = wo + (size_t)E * E;              // 192M (384 MB)
  unsigned short* att = qkv + (size_t)NTOK * 3 * E;      // 64M (128 MB)

  cvt8<<<(NTOK * E / 8) / 256, 256, 0, stream>>>(x, xb, NTOK * E / 8);
  cvtW<<<(4 * E * E / 8) / 256, 256, 0, stream>>>(Wq, Wk, Wv, Wo, wqkv);

  // QKV: [65536,1024] x [3072,1024]^T -> [65536,3072]
  gemm8<unsigned short><<<(NTOK / 256) * (3 * E / 256), 512, 0, stream>>>(
      xb, wqkv, qkv, NTOK, 3 * E, E, 3 * E / 256);

  attn16<<<NTOK / 4, 256, 0, stream>>>(qkv, att);

  // O-proj: [65536,1024] x [1024,1024]^T -> fp32
  gemm8<float><<<(NTOK / 256) * (E / 256), 512, 0, stream>>>(
      att, wo, (float*)d_out, NTOK, E, E, E / 256);
}